// Round 1
// baseline (115.820 us; speedup 1.0000x reference)
//
#include <hip/hip_runtime.h>

#define NB    128   // batch = attention length L
#define SEQ   512
#define EMB   768
#define NH    16
#define DHEAD 48
#define LMAXN 5
#define K3E   2304  // 3*EMB

// ---------------------------------------------------------------- pun -------
__global__ __launch_bounds__(256) void pun_kernel(
    const float* __restrict__ lhs, const int* __restrict__ loc,
    float* __restrict__ pun)
{
  int b = blockIdx.x;
  int idxs[LMAXN];
  int cnt = 0;
#pragma unroll
  for (int j = 0; j < LMAXN; j++) {
    int v = loc[b * LMAXN + j];
    idxs[j] = v;
    if (v >= 0) cnt++;
  }
  float inv = 1.0f / (float)cnt;
  for (int e = threadIdx.x; e < EMB; e += 256) {
    float s = 0.0f;
#pragma unroll
    for (int j = 0; j < LMAXN; j++) {
      if (idxs[j] >= 0) s += lhs[((size_t)b * SEQ + idxs[j]) * EMB + e];
    }
    pun[b * EMB + e] = s * inv;
  }
}

// -------------------------------------------------- generic GEMM + bias ----
// C[128,N] = A[128,768] @ Bw[N,768]^T + bias[N]
// BM=32, BN=64, BK=32, 256 threads, 2x4 microtile.
__global__ __launch_bounds__(256) void gemm_bias(
    const float* __restrict__ A, const float* __restrict__ Bw,
    const float* __restrict__ bias, float* __restrict__ C, int N)
{
  __shared__ float As[32][36];  // [k][m], +4 pad: conflict-free
  __shared__ float Bs[32][68];  // [k][n], +4 pad
  int t  = threadIdx.x;
  int bm = blockIdx.y * 32;
  int bn = blockIdx.x * 64;
  int r  = t >> 3;        // 0..31
  int c4 = (t & 7) * 4;   // k offset 0..28
  int tx = t & 15;        // n-group
  int ty = t >> 4;        // m-group
  float acc[2][4] = {};

  for (int k0 = 0; k0 < 768; k0 += 32) {
    float4 av = *(const float4*)&A[(size_t)(bm + r) * 768 + k0 + c4];
    float4 bv0 = make_float4(0.f, 0.f, 0.f, 0.f);
    float4 bv1 = make_float4(0.f, 0.f, 0.f, 0.f);
    int n0 = bn + r, n1 = bn + r + 32;
    if (n0 < N) bv0 = *(const float4*)&Bw[(size_t)n0 * 768 + k0 + c4];
    if (n1 < N) bv1 = *(const float4*)&Bw[(size_t)n1 * 768 + k0 + c4];
    __syncthreads();
    As[c4 + 0][r] = av.x; As[c4 + 1][r] = av.y;
    As[c4 + 2][r] = av.z; As[c4 + 3][r] = av.w;
    Bs[c4 + 0][r] = bv0.x; Bs[c4 + 1][r] = bv0.y;
    Bs[c4 + 2][r] = bv0.z; Bs[c4 + 3][r] = bv0.w;
    Bs[c4 + 0][r + 32] = bv1.x; Bs[c4 + 1][r + 32] = bv1.y;
    Bs[c4 + 2][r + 32] = bv1.z; Bs[c4 + 3][r + 32] = bv1.w;
    __syncthreads();
#pragma unroll
    for (int kk = 0; kk < 32; kk++) {
      float2 a = *(const float2*)&As[kk][ty * 2];
      float4 b = *(const float4*)&Bs[kk][tx * 4];
      acc[0][0] += a.x * b.x; acc[0][1] += a.x * b.y;
      acc[0][2] += a.x * b.z; acc[0][3] += a.x * b.w;
      acc[1][0] += a.y * b.x; acc[1][1] += a.y * b.y;
      acc[1][2] += a.y * b.z; acc[1][3] += a.y * b.w;
    }
  }
  int m = bm + ty * 2;
  int n = bn + tx * 4;
#pragma unroll
  for (int j = 0; j < 4; j++) {
    if (n + j < N) {
      float bb = bias[n + j];
      C[(size_t)m * N + n + j]       = acc[0][j] + bb;
      C[(size_t)(m + 1) * N + n + j] = acc[1][j] + bb;
    }
  }
}

// ----------------------------------------------------------- attention -----
// grid (NH, 4): one block per (head, 32-row l-tile). 256 threads.
// Only token n=0 matters: q,k,v rows all come from proj (pun projection).
__global__ __launch_bounds__(256) void attn_kernel(
    const float* __restrict__ proj, float* __restrict__ ctx)
{
  __shared__ float ks[128][52];  // pad 48->52: conflict-free strided reads
  __shared__ float vs[128][52];
  int h  = blockIdx.x;
  int l0 = blockIdx.y * 32;
  int t  = threadIdx.x;

  // stage K, V for this head (all 128 batch rows)
  for (int i = t; i < 128 * 12; i += 256) {
    int m  = i / 12;
    int dd = (i - m * 12) * 4;
    float4 kv = *(const float4*)&proj[(size_t)m * K3E + EMB     + h * DHEAD + dd];
    float4 vv = *(const float4*)&proj[(size_t)m * K3E + 2 * EMB + h * DHEAD + dd];
    *(float4*)&ks[m][dd] = kv;
    *(float4*)&vs[m][dd] = vv;
  }

  int l  = t >> 3;   // 0..31 row within tile
  int g  = t & 7;    // 8 threads cooperate per row
  int lg = l0 + l;
  const float scale = 0.14433756729740643f;  // 48^-0.5
  float q[48];
#pragma unroll
  for (int jj = 0; jj < 12; jj++) {
    float4 qv = *(const float4*)&proj[(size_t)lg * K3E + h * DHEAD + jj * 4];
    q[jj * 4 + 0] = qv.x * scale; q[jj * 4 + 1] = qv.y * scale;
    q[jj * 4 + 2] = qv.z * scale; q[jj * 4 + 3] = qv.w * scale;
  }
  __syncthreads();

  // scores: thread handles m = g + 8*jm
  float sv[16];
  float smax = -1e30f;
#pragma unroll
  for (int jm = 0; jm < 16; jm++) {
    int m = g + jm * 8;
    float s = 0.0f;
#pragma unroll
    for (int dq = 0; dq < 12; dq++) {
      float4 kv = *(const float4*)&ks[m][dq * 4];
      s += q[dq * 4 + 0] * kv.x + q[dq * 4 + 1] * kv.y +
           q[dq * 4 + 2] * kv.z + q[dq * 4 + 3] * kv.w;
    }
    sv[jm] = s;
    smax = fmaxf(smax, s);
  }
#pragma unroll
  for (int off = 1; off < 8; off <<= 1) smax = fmaxf(smax, __shfl_xor(smax, off));
  float ssum = 0.0f;
#pragma unroll
  for (int jm = 0; jm < 16; jm++) { float e = __expf(sv[jm] - smax); sv[jm] = e; ssum += e; }
#pragma unroll
  for (int off = 1; off < 8; off <<= 1) ssum += __shfl_xor(ssum, off);
  float inv = 1.0f / ssum;
#pragma unroll
  for (int jm = 0; jm < 16; jm++) sv[jm] *= inv;

  // PV: per-thread partial over its 16 m's, all 48 d's
  float acc[48] = {};
#pragma unroll
  for (int jm = 0; jm < 16; jm++) {
    int m = g + jm * 8;
    float p = sv[jm];
#pragma unroll
    for (int dq = 0; dq < 12; dq++) {
      float4 vv = *(const float4*)&vs[m][dq * 4];
      acc[dq * 4 + 0] += p * vv.x; acc[dq * 4 + 1] += p * vv.y;
      acc[dq * 4 + 2] += p * vv.z; acc[dq * 4 + 3] += p * vv.w;
    }
  }

  // recursive-halving butterfly over the 8 row-threads; all register indices
  // compile-time (rule: runtime-indexed reg arrays spill to scratch).
  {
    float buf[24];
    if (g & 4) {
#pragma unroll
      for (int d = 0; d < 24; d++) buf[d] = acc[d];
    } else {
#pragma unroll
      for (int d = 0; d < 24; d++) buf[d] = acc[d + 24];
    }
#pragma unroll
    for (int d = 0; d < 24; d++) buf[d] = __shfl_xor(buf[d], 4);
    if (g & 4) {
#pragma unroll
      for (int d = 0; d < 24; d++) acc[d] = acc[d + 24] + buf[d];
    } else {
#pragma unroll
      for (int d = 0; d < 24; d++) acc[d] = acc[d] + buf[d];
    }
  }
  {
    float buf[12];
    if (g & 2) {
#pragma unroll
      for (int d = 0; d < 12; d++) buf[d] = acc[d];
    } else {
#pragma unroll
      for (int d = 0; d < 12; d++) buf[d] = acc[d + 12];
    }
#pragma unroll
    for (int d = 0; d < 12; d++) buf[d] = __shfl_xor(buf[d], 2);
    if (g & 2) {
#pragma unroll
      for (int d = 0; d < 12; d++) acc[d] = acc[d + 12] + buf[d];
    } else {
#pragma unroll
      for (int d = 0; d < 12; d++) acc[d] = acc[d] + buf[d];
    }
  }
  {
    float buf[6];
    if (g & 1) {
#pragma unroll
      for (int d = 0; d < 6; d++) buf[d] = acc[d];
    } else {
#pragma unroll
      for (int d = 0; d < 6; d++) buf[d] = acc[d + 6];
    }
#pragma unroll
    for (int d = 0; d < 6; d++) buf[d] = __shfl_xor(buf[d], 1);
    if (g & 1) {
#pragma unroll
      for (int d = 0; d < 6; d++) acc[d] = acc[d + 6] + buf[d];
    } else {
#pragma unroll
      for (int d = 0; d < 6; d++) acc[d] = acc[d] + buf[d];
    }
  }
  // thread (l,g) now holds fully-reduced d = g*6 .. g*6+5 in acc[0..5]
#pragma unroll
  for (int j = 0; j < 6; j++) {
    ctx[(size_t)lg * EMB + h * DHEAD + g * 6 + j] = acc[j];
  }
}

// ---------------------------------------------------------------------------
extern "C" void kernel_launch(void* const* d_in, const int* in_sizes, int n_in,
                              void* d_out, int out_size, void* d_ws, size_t ws_size,
                              hipStream_t stream) {
  const float* lhs   = (const float*)d_in[0];
  // d_in[1] sense_emb: dead — only attn_out[:,0,:] is used, which depends
  // solely on the pun token's q/k/v.
  const int*   loc   = (const int*)  d_in[2];
  const float* w_in  = (const float*)d_in[3];
  const float* b_in  = (const float*)d_in[4];
  const float* w_out = (const float*)d_in[5];
  const float* b_out = (const float*)d_in[6];
  const float* w_lin = (const float*)d_in[7];
  const float* b_lin = (const float*)d_in[8];
  float* out = (float*)d_out;

  char* ws = (char*)d_ws;
  float* pun      = (float*)(ws);                               // 128*768
  float* proj     = (float*)(ws + 393216);                      // 128*2304
  float* ctx      = (float*)(ws + 393216 + 1179648);            // 128*768
  float* attn_out = (float*)(ws + 393216 + 1179648 + 393216);   // 128*768

  pun_kernel<<<128, 256, 0, stream>>>(lhs, loc, pun);
  gemm_bias<<<dim3(36, 4), 256, 0, stream>>>(pun, w_in, b_in, proj, K3E);
  attn_kernel<<<dim3(NH, 4), 256, 0, stream>>>(proj, ctx);
  gemm_bias<<<dim3(12, 4), 256, 0, stream>>>(ctx, w_out, b_out, attn_out, EMB);
  gemm_bias<<<dim3(2, 4), 256, 0, stream>>>(attn_out, w_lin, b_lin, out, 100);
}

// Round 2
// 98.154 us; speedup vs baseline: 1.1800x; 1.1800x over previous
//
#include <hip/hip_runtime.h>

#define SEQ   512
#define EMB   768
#define K3E   2304
#define NH    16
#define DHD   48
#define LMAXN 5

// ---------- fused pun-gather + GEMM1 ---------------------------------------
// proj[128,2304] = pun[128,768] @ Win[2304,768]^T + bin
// BM=16, BN=64, BK=32, 256 threads, 1x4 microtile. grid (36, 8)
__global__ __launch_bounds__(256) void gemm1_fused(
    const float* __restrict__ lhs, const int* __restrict__ loc,
    const float* __restrict__ Bw, const float* __restrict__ bias,
    float* __restrict__ C)
{
  __shared__ float As[2][32][20];
  __shared__ float Bs[2][32][68];
  __shared__ int   sloc[16][LMAXN];
  __shared__ float sinv[16];
  int t  = threadIdx.x;
  int bm = blockIdx.y * 16;
  int bn = blockIdx.x * 64;

  if (t < 16) {
    int cnt = 0;
#pragma unroll
    for (int j = 0; j < LMAXN; j++) {
      int v = loc[(bm + t) * LMAXN + j];
      sloc[t][j] = v;
      if (v >= 0) cnt++;
    }
    sinv[t] = 1.0f / (float)cnt;
  }
  __syncthreads();

  int ar = t >> 4;         // A row 0..15
  int ac = (t & 15) * 2;   // A k-col 0..30
  int br = t >> 3;         // B row 0..31 (+32 for second)
  int bc = (t & 7) * 4;    // B k-col
  int tx = t & 15, ty = t >> 4;

  float2 a_reg;
  float4 b_reg0, b_reg1;

  // prologue loads (tile 0)
  {
    float sx = 0.f, sy = 0.f;
#pragma unroll
    for (int j = 0; j < LMAXN; j++) {
      int v = sloc[ar][j];
      if (v >= 0) {
        float2 w = *(const float2*)&lhs[((size_t)(bm + ar) * SEQ + v) * EMB + ac];
        sx += w.x; sy += w.y;
      }
    }
    a_reg = make_float2(sx * sinv[ar], sy * sinv[ar]);
    b_reg0 = *(const float4*)&Bw[(size_t)(bn + br) * EMB + bc];
    b_reg1 = *(const float4*)&Bw[(size_t)(bn + br + 32) * EMB + bc];
  }

  float acc[4] = {};
  int buf = 0;
  for (int t0 = 0; t0 < 24; ++t0) {
    // write current regs to lds[buf] (safe: nobody reads buf right now)
    As[buf][ac][ar]     = a_reg.x;
    As[buf][ac + 1][ar] = a_reg.y;
    Bs[buf][bc + 0][br] = b_reg0.x; Bs[buf][bc + 1][br] = b_reg0.y;
    Bs[buf][bc + 2][br] = b_reg0.z; Bs[buf][bc + 3][br] = b_reg0.w;
    Bs[buf][bc + 0][br + 32] = b_reg1.x; Bs[buf][bc + 1][br + 32] = b_reg1.y;
    Bs[buf][bc + 2][br + 32] = b_reg1.z; Bs[buf][bc + 3][br + 32] = b_reg1.w;
    __syncthreads();
    if (t0 < 23) {
      int k0 = (t0 + 1) * 32;
      float sx = 0.f, sy = 0.f;
#pragma unroll
      for (int j = 0; j < LMAXN; j++) {
        int v = sloc[ar][j];
        if (v >= 0) {
          float2 w = *(const float2*)&lhs[((size_t)(bm + ar) * SEQ + v) * EMB + k0 + ac];
          sx += w.x; sy += w.y;
        }
      }
      a_reg = make_float2(sx * sinv[ar], sy * sinv[ar]);
      b_reg0 = *(const float4*)&Bw[(size_t)(bn + br) * EMB + k0 + bc];
      b_reg1 = *(const float4*)&Bw[(size_t)(bn + br + 32) * EMB + k0 + bc];
    }
#pragma unroll
    for (int kk = 0; kk < 32; kk++) {
      float a  = As[buf][kk][ty];
      float4 b = *(const float4*)&Bs[buf][kk][tx * 4];
      acc[0] += a * b.x; acc[1] += a * b.y;
      acc[2] += a * b.z; acc[3] += a * b.w;
    }
    buf ^= 1;
  }
  int m = bm + ty, n = bn + tx * 4;
  float4 bb = *(const float4*)&bias[n];
  float4 o = make_float4(acc[0] + bb.x, acc[1] + bb.y, acc[2] + bb.z, acc[3] + bb.w);
  *(float4*)&C[(size_t)m * K3E + n] = o;
}

// ---------- generic small GEMM: C[128,N] = A[128,768] @ Bw[N,768]^T + bias --
// BK=32, 256 threads, TM=1. threads = BM * (BN/TN) must equal 256.
template<int BM, int BN, int TN, int LDC>
__global__ __launch_bounds__(256) void gemm_bias(
    const float* __restrict__ A, const float* __restrict__ Bw,
    const float* __restrict__ bias, float* __restrict__ C, int N)
{
  __shared__ float As[2][32][BM + 4];
  __shared__ float Bs[2][32][BN + 4];
  int t  = threadIdx.x;
  int bm = blockIdx.y * BM;
  int bn = blockIdx.x * BN;

  // A-tile: BM x 32 floats
  constexpr int APT = (BM * 32) / 256;  // floats per thread (1 or 2)
  int ar, ac;
  if constexpr (APT == 2) { ar = t >> 4; ac = (t & 15) * 2; }
  else                    { ar = t >> 5; ac = (t & 31); }
  // B-tile: BN x 32 = 1024 floats -> float4 per thread (BN==32)
  static_assert(BN == 32, "loader assumes BN==32");
  int br = t >> 3;
  int bc = (t & 7) * 4;
  int tx = t % (BN / TN);
  int ty = t / (BN / TN);

  float  a0 = 0.f, a1 = 0.f;
  float4 b_reg;

  auto loadT = [&](int k0) {
    if constexpr (APT == 2) {
      float2 w = *(const float2*)&A[(size_t)(bm + ar) * EMB + k0 + ac];
      a0 = w.x; a1 = w.y;
    } else {
      a0 = A[(size_t)(bm + ar) * EMB + k0 + ac];
    }
    if (bn + br < N) b_reg = *(const float4*)&Bw[(size_t)(bn + br) * EMB + k0 + bc];
    else             b_reg = make_float4(0.f, 0.f, 0.f, 0.f);
  };

  loadT(0);
  float acc[TN] = {};
  int buf = 0;
  for (int t0 = 0; t0 < 24; ++t0) {
    if constexpr (APT == 2) {
      As[buf][ac][ar] = a0; As[buf][ac + 1][ar] = a1;
    } else {
      As[buf][ac][ar] = a0;
    }
    Bs[buf][bc + 0][br] = b_reg.x; Bs[buf][bc + 1][br] = b_reg.y;
    Bs[buf][bc + 2][br] = b_reg.z; Bs[buf][bc + 3][br] = b_reg.w;
    __syncthreads();
    if (t0 < 23) loadT((t0 + 1) * 32);
#pragma unroll
    for (int kk = 0; kk < 32; kk++) {
      float a = As[buf][kk][ty];
#pragma unroll
      for (int j = 0; j < TN; j++) {
        acc[j] += a * Bs[buf][kk][tx * TN + j];
      }
    }
    buf ^= 1;
  }
  int m = bm + ty;
#pragma unroll
  for (int j = 0; j < TN; j++) {
    int n = bn + tx * TN + j;
    if (n < N) C[(size_t)m * LDC + n] = acc[j] + bias[n];
  }
}

// ---------- attention (only token 0's output matters) -----------------------
// grid (NH, 8): one block per (head, 16-row l-tile). 256 threads.
__global__ __launch_bounds__(256) void attn_kernel(
    const float* __restrict__ proj, float* __restrict__ ctx)
{
  __shared__ float ks[128][52];
  __shared__ float vs[128][52];
  int h  = blockIdx.x;
  int l0 = blockIdx.y * 16;
  int t  = threadIdx.x;

  for (int i = t; i < 128 * 12; i += 256) {
    int m  = i / 12;
    int dd = (i - m * 12) * 4;
    float4 kv = *(const float4*)&proj[(size_t)m * K3E + EMB     + h * DHD + dd];
    float4 vv = *(const float4*)&proj[(size_t)m * K3E + 2 * EMB + h * DHD + dd];
    *(float4*)&ks[m][dd] = kv;
    *(float4*)&vs[m][dd] = vv;
  }

  int l  = t >> 4;     // 0..15 row within tile
  int g  = t & 15;     // 16 threads per row
  int lg = l0 + l;
  const float scale = 0.14433756729740643f;  // 48^-0.5
  float q[48];
#pragma unroll
  for (int jj = 0; jj < 12; jj++) {
    float4 qv = *(const float4*)&proj[(size_t)lg * K3E + h * DHD + jj * 4];
    q[jj * 4 + 0] = qv.x * scale; q[jj * 4 + 1] = qv.y * scale;
    q[jj * 4 + 2] = qv.z * scale; q[jj * 4 + 3] = qv.w * scale;
  }
  __syncthreads();

  float sv[8];
  float smax = -1e30f;
#pragma unroll
  for (int jm = 0; jm < 8; jm++) {
    int m = g + jm * 16;
    float s = 0.0f;
#pragma unroll
    for (int dq = 0; dq < 12; dq++) {
      float4 kv = *(const float4*)&ks[m][dq * 4];
      s += q[dq * 4 + 0] * kv.x + q[dq * 4 + 1] * kv.y +
           q[dq * 4 + 2] * kv.z + q[dq * 4 + 3] * kv.w;
    }
    sv[jm] = s;
    smax = fmaxf(smax, s);
  }
#pragma unroll
  for (int off = 1; off < 16; off <<= 1) smax = fmaxf(smax, __shfl_xor(smax, off));
  float ssum = 0.0f;
#pragma unroll
  for (int jm = 0; jm < 8; jm++) { float e = __expf(sv[jm] - smax); sv[jm] = e; ssum += e; }
#pragma unroll
  for (int off = 1; off < 16; off <<= 1) ssum += __shfl_xor(ssum, off);
  float inv = 1.0f / ssum;
#pragma unroll
  for (int jm = 0; jm < 8; jm++) sv[jm] *= inv;

  float acc[48] = {};
#pragma unroll
  for (int jm = 0; jm < 8; jm++) {
    int m = g + jm * 16;
    float p = sv[jm];
#pragma unroll
    for (int dq = 0; dq < 12; dq++) {
      float4 vv = *(const float4*)&vs[m][dq * 4];
      acc[dq * 4 + 0] += p * vv.x; acc[dq * 4 + 1] += p * vv.y;
      acc[dq * 4 + 2] += p * vv.z; acc[dq * 4 + 3] += p * vv.w;
    }
  }

  // butterfly over 16 row-threads; compile-time register indices throughout.
  {
    float buf[24];
    if (g & 8) { 
#pragma unroll
      for (int d = 0; d < 24; d++) buf[d] = acc[d];
    } else {
#pragma unroll
      for (int d = 0; d < 24; d++) buf[d] = acc[d + 24];
    }
#pragma unroll
    for (int d = 0; d < 24; d++) buf[d] = __shfl_xor(buf[d], 8);
    if (g & 8) {
#pragma unroll
      for (int d = 0; d < 24; d++) acc[d] = acc[d + 24] + buf[d];
    } else {
#pragma unroll
      for (int d = 0; d < 24; d++) acc[d] = acc[d] + buf[d];
    }
  }
  {
    float buf[12];
    if (g & 4) {
#pragma unroll
      for (int d = 0; d < 12; d++) buf[d] = acc[d];
    } else {
#pragma unroll
      for (int d = 0; d < 12; d++) buf[d] = acc[d + 12];
    }
#pragma unroll
    for (int d = 0; d < 12; d++) buf[d] = __shfl_xor(buf[d], 4);
    if (g & 4) {
#pragma unroll
      for (int d = 0; d < 12; d++) acc[d] = acc[d + 12] + buf[d];
    } else {
#pragma unroll
      for (int d = 0; d < 12; d++) acc[d] = acc[d] + buf[d];
    }
  }
  {
    float buf[6];
    if (g & 2) {
#pragma unroll
      for (int d = 0; d < 6; d++) buf[d] = acc[d];
    } else {
#pragma unroll
      for (int d = 0; d < 6; d++) buf[d] = acc[d + 6];
    }
#pragma unroll
    for (int d = 0; d < 6; d++) buf[d] = __shfl_xor(buf[d], 2);
    if (g & 2) {
#pragma unroll
      for (int d = 0; d < 6; d++) acc[d] = acc[d + 6] + buf[d];
    } else {
#pragma unroll
      for (int d = 0; d < 6; d++) acc[d] = acc[d] + buf[d];
    }
  }
  {
    float buf[3];
    if (g & 1) {
#pragma unroll
      for (int d = 0; d < 3; d++) buf[d] = acc[d];
    } else {
#pragma unroll
      for (int d = 0; d < 3; d++) buf[d] = acc[d + 3];
    }
#pragma unroll
    for (int d = 0; d < 3; d++) buf[d] = __shfl_xor(buf[d], 1);
    if (g & 1) {
#pragma unroll
      for (int d = 0; d < 3; d++) acc[d] = acc[d + 3] + buf[d];
    } else {
#pragma unroll
      for (int d = 0; d < 3; d++) acc[d] = acc[d] + buf[d];
    }
  }
  // thread (l,g) holds d = g*3 .. g*3+2
#pragma unroll
  for (int j = 0; j < 3; j++) {
    ctx[(size_t)lg * EMB + h * DHD + g * 3 + j] = acc[j];
  }
}

// ---------------------------------------------------------------------------
extern "C" void kernel_launch(void* const* d_in, const int* in_sizes, int n_in,
                              void* d_out, int out_size, void* d_ws, size_t ws_size,
                              hipStream_t stream) {
  const float* lhs   = (const float*)d_in[0];
  // d_in[1] sense_emb: dead — only attn_out[:,0,:] is used downstream.
  const int*   loc   = (const int*)  d_in[2];
  const float* w_in  = (const float*)d_in[3];
  const float* b_in  = (const float*)d_in[4];
  const float* w_out = (const float*)d_in[5];
  const float* b_out = (const float*)d_in[6];
  const float* w_lin = (const float*)d_in[7];
  const float* b_lin = (const float*)d_in[8];
  float* out = (float*)d_out;

  char* ws = (char*)d_ws;
  float* proj     = (float*)(ws);                       // 128*2304
  float* ctx      = (float*)(ws + 1179648);             // 128*768
  float* attn_out = (float*)(ws + 1179648 + 393216);    // 128*768

  gemm1_fused<<<dim3(36, 8), 256, 0, stream>>>(lhs, loc, w_in, b_in, proj);
  attn_kernel<<<dim3(NH, 8), 256, 0, stream>>>(proj, ctx);
  gemm_bias<16, 32, 2, EMB><<<dim3(24, 8), 256, 0, stream>>>(ctx, w_out, b_out, attn_out, EMB);
  gemm_bias<8, 32, 1, 100><<<dim3(4, 16), 256, 0, stream>>>(attn_out, w_lin, b_lin, out, 100);
}

// Round 3
// 56.748 us; speedup vs baseline: 2.0410x; 1.7296x over previous
//
#include <hip/hip_runtime.h>

#define SEQ   512
#define EMB   768
#define K3E   2304
#define NH    16
#define DHD   48

// ============================================================================
// GEMM1 (fused pun gather): proj[128,2304] = pun @ W_in^T + b_in
// Tile 16x64 per block, 256 thr = 4 waves, each wave owns a K=192 slice
// (12 steps of BK=16) with wave-private double-buffered LDS (no barriers in
// the K-loop). 4x4 microtile: 16 FMA per (1 b128 A + 1 b128 B) read.
// Cross-wave reduce via LDS at the end (one __syncthreads).
// grid (36, 8) = 288 blocks.
// LDS layout (floats): per wave (stride 2816): A[2][16][20]=640, B[2][16][68]=2176
//   red at 11264: [4][1024]. Total 15360 floats = 60 KB -> 2 blocks/CU.
// ============================================================================
__global__ __launch_bounds__(256) void gemm1_fused(
    const float* __restrict__ lhs, const int* __restrict__ loc,
    const float* __restrict__ Bw, const float* __restrict__ bias,
    float* __restrict__ C)
{
  __shared__ float lds[15360];
  const int t  = threadIdx.x;
  const int w  = t >> 6, l = t & 63;
  const int bm = blockIdx.y * 16, bn = blockIdx.x * 64;
  const int tx = l & 15, ty = l >> 4;      // frag: n=tx*4.., m=ty*4..
  const int gm = l & 15, gq = l >> 4;      // A-staging: row, k-quad
  const int kbase = w * 192;
  const int AW = w * 2816;
  const int BW = w * 2816 + 640;

  // gather metadata for row bm+gm (held in registers, reused all steps)
  int locs[5]; int cnt = 0;
#pragma unroll
  for (int j = 0; j < 5; j++) {
    int v = loc[(bm + gm) * 5 + j];
    locs[j] = v; if (v >= 0) cnt++;
  }
  const float ginv = 1.0f / (float)cnt;
  const float* lrow = lhs + (size_t)(bm + gm) * SEQ * EMB;
  const float* brow = Bw + (size_t)(bn + l) * EMB;

  float4 aF, bF0, bF1, bF2, bF3;

#define G1_LOAD(s) {                                                          \
    int k0 = kbase + (s) * 16;                                                \
    float sx=0.f, sy=0.f, sz=0.f, sw=0.f;                                     \
    _Pragma("unroll")                                                         \
    for (int j = 0; j < 5; j++) {                                             \
      int v = locs[j] >= 0 ? locs[j] : 0;                                     \
      float4 wv = *(const float4*)&lrow[(size_t)v * EMB + k0 + gq * 4];       \
      if (locs[j] >= 0) { sx+=wv.x; sy+=wv.y; sz+=wv.z; sw+=wv.w; }           \
    }                                                                         \
    aF = make_float4(sx*ginv, sy*ginv, sz*ginv, sw*ginv);                     \
    bF0 = *(const float4*)&brow[k0 + 0];                                      \
    bF1 = *(const float4*)&brow[k0 + 4];                                      \
    bF2 = *(const float4*)&brow[k0 + 8];                                      \
    bF3 = *(const float4*)&brow[k0 + 12]; }

#define G1_WRITE(b) {                                                         \
    int Ab = AW + (b) * 320;                                                  \
    lds[Ab + (gq*4+0)*20 + gm] = aF.x;                                        \
    lds[Ab + (gq*4+1)*20 + gm] = aF.y;                                        \
    lds[Ab + (gq*4+2)*20 + gm] = aF.z;                                        \
    lds[Ab + (gq*4+3)*20 + gm] = aF.w;                                        \
    int Bb = BW + (b) * 1088;                                                 \
    lds[Bb +  0*68 + l] = bF0.x; lds[Bb +  1*68 + l] = bF0.y;                 \
    lds[Bb +  2*68 + l] = bF0.z; lds[Bb +  3*68 + l] = bF0.w;                 \
    lds[Bb +  4*68 + l] = bF1.x; lds[Bb +  5*68 + l] = bF1.y;                 \
    lds[Bb +  6*68 + l] = bF1.z; lds[Bb +  7*68 + l] = bF1.w;                 \
    lds[Bb +  8*68 + l] = bF2.x; lds[Bb +  9*68 + l] = bF2.y;                 \
    lds[Bb + 10*68 + l] = bF2.z; lds[Bb + 11*68 + l] = bF2.w;                 \
    lds[Bb + 12*68 + l] = bF3.x; lds[Bb + 13*68 + l] = bF3.y;                 \
    lds[Bb + 14*68 + l] = bF3.z; lds[Bb + 15*68 + l] = bF3.w; }

  float acc[4][4] = {};
  G1_LOAD(0); G1_WRITE(0);
  for (int s = 0; s < 12; s++) {
    int b = s & 1;
    if (s < 11) G1_LOAD(s + 1);          // prefetch into regs (latency hidden)
    int Ab = AW + b * 320, Bb = BW + b * 1088;
#pragma unroll
    for (int kk = 0; kk < 16; kk++) {
      float4 a  = *(float4*)&lds[Ab + kk * 20 + ty * 4];
      float4 bb = *(float4*)&lds[Bb + kk * 68 + tx * 4];
      acc[0][0] += a.x*bb.x; acc[0][1] += a.x*bb.y; acc[0][2] += a.x*bb.z; acc[0][3] += a.x*bb.w;
      acc[1][0] += a.y*bb.x; acc[1][1] += a.y*bb.y; acc[1][2] += a.y*bb.z; acc[1][3] += a.y*bb.w;
      acc[2][0] += a.z*bb.x; acc[2][1] += a.z*bb.y; acc[2][2] += a.z*bb.z; acc[2][3] += a.z*bb.w;
      acc[3][0] += a.w*bb.x; acc[3][1] += a.w*bb.y; acc[3][2] += a.w*bb.z; acc[3][3] += a.w*bb.w;
    }
    if (s < 11) G1_WRITE(b ^ 1);         // same-wave dbuf: no barrier needed
  }

  // cross-wave reduce (red region disjoint from staging -> single barrier)
  int Rb = 11264 + w * 1024;
#pragma unroll
  for (int i = 0; i < 4; i++)
    *(float4*)&lds[Rb + (ty*4 + i) * 64 + tx * 4] =
        make_float4(acc[i][0], acc[i][1], acc[i][2], acc[i][3]);
  __syncthreads();
  int o = t * 4;
  int m = o >> 6, n = o & 63;
  float4 s0 = *(float4*)&lds[11264 + 0*1024 + o];
  float4 s1 = *(float4*)&lds[11264 + 1*1024 + o];
  float4 s2 = *(float4*)&lds[11264 + 2*1024 + o];
  float4 s3 = *(float4*)&lds[11264 + 3*1024 + o];
  float4 bb = *(const float4*)&bias[bn + n];
  float4 r = make_float4(s0.x+s1.x+s2.x+s3.x+bb.x, s0.y+s1.y+s2.y+s3.y+bb.y,
                         s0.z+s1.z+s2.z+s3.z+bb.z, s0.w+s1.w+s2.w+s3.w+bb.w);
  *(float4*)&C[(size_t)(bm + m) * K3E + bn + n] = r;
#undef G1_LOAD
#undef G1_WRITE
}

// ============================================================================
// Generic reduced GEMM: C[128,N] = A[128,768] @ Bw[N,768]^T + bias  (N<=grid*32)
// Tile 16x32, 4 waves split K=768 into 4x192, wave-private dbuf LDS, 2x4
// microtile. One barrier. LDS: per wave (stride 1792): A[2][16][20]=640,
// B[2][16][36]=1152; red at 7168: [4][512]. 9216 floats = 36 KB.
// ============================================================================
__global__ __launch_bounds__(256) void gemm_red(
    const float* __restrict__ A, const float* __restrict__ Bw,
    const float* __restrict__ bias, float* __restrict__ C,
    int N, int LDC)
{
  __shared__ float lds[9216];
  const int t  = threadIdx.x;
  const int w  = t >> 6, l = t & 63;
  const int bm = blockIdx.y * 16, bn = blockIdx.x * 32;
  const int tx = l & 7, ty = l >> 3;       // frag: n=tx*4.., m=ty*2..
  const int am = l & 15, aq = l >> 4;      // A-staging: row, k-quad
  const int bl = l & 31, bh = l >> 5;      // B-staging: row, k-half
  const int kbase = w * 192;
  const int AW = w * 1792;
  const int BW = w * 1792 + 640;

  const float* arow = A + (size_t)(bm + am) * EMB;
  const int brg = bn + bl;
  const bool bok = brg < N;
  const float* brow = Bw + (size_t)(bok ? brg : (N - 1)) * EMB;

  float4 aF, bF0, bF1;

#define G2_LOAD(s) {                                                          \
    int k0 = kbase + (s) * 16;                                                \
    aF = *(const float4*)&arow[k0 + aq * 4];                                  \
    if (bok) {                                                                \
      bF0 = *(const float4*)&brow[k0 + bh * 8 + 0];                           \
      bF1 = *(const float4*)&brow[k0 + bh * 8 + 4];                           \
    } else {                                                                  \
      bF0 = make_float4(0.f,0.f,0.f,0.f); bF1 = bF0;                          \
    } }

#define G2_WRITE(b) {                                                         \
    int Ab = AW + (b) * 320;                                                  \
    lds[Ab + (aq*4+0)*20 + am] = aF.x;                                        \
    lds[Ab + (aq*4+1)*20 + am] = aF.y;                                        \
    lds[Ab + (aq*4+2)*20 + am] = aF.z;                                        \
    lds[Ab + (aq*4+3)*20 + am] = aF.w;                                        \
    int Bb = BW + (b) * 576;                                                  \
    lds[Bb + (bh*8+0)*36 + bl] = bF0.x; lds[Bb + (bh*8+1)*36 + bl] = bF0.y;   \
    lds[Bb + (bh*8+2)*36 + bl] = bF0.z; lds[Bb + (bh*8+3)*36 + bl] = bF0.w;   \
    lds[Bb + (bh*8+4)*36 + bl] = bF1.x; lds[Bb + (bh*8+5)*36 + bl] = bF1.y;   \
    lds[Bb + (bh*8+6)*36 + bl] = bF1.z; lds[Bb + (bh*8+7)*36 + bl] = bF1.w; }

  float acc[2][4] = {};
  G2_LOAD(0); G2_WRITE(0);
  for (int s = 0; s < 12; s++) {
    int b = s & 1;
    if (s < 11) G2_LOAD(s + 1);
    int Ab = AW + b * 320, Bb = BW + b * 576;
#pragma unroll
    for (int kk = 0; kk < 16; kk++) {
      float2 a  = *(float2*)&lds[Ab + kk * 20 + ty * 2];
      float4 bb = *(float4*)&lds[Bb + kk * 36 + tx * 4];
      acc[0][0] += a.x*bb.x; acc[0][1] += a.x*bb.y; acc[0][2] += a.x*bb.z; acc[0][3] += a.x*bb.w;
      acc[1][0] += a.y*bb.x; acc[1][1] += a.y*bb.y; acc[1][2] += a.y*bb.z; acc[1][3] += a.y*bb.w;
    }
    if (s < 11) G2_WRITE(b ^ 1);
  }

  int Rb = 7168 + w * 512;
#pragma unroll
  for (int i = 0; i < 2; i++)
    *(float4*)&lds[Rb + (ty*2 + i) * 32 + tx * 4] =
        make_float4(acc[i][0], acc[i][1], acc[i][2], acc[i][3]);
  __syncthreads();
  int o = t * 2;
  int m = o >> 5, n = o & 31;
#pragma unroll
  for (int j = 0; j < 2; j++) {
    int ng = bn + n + j;
    if (ng < N) {
      float v = lds[7168 + 0*512 + o + j] + lds[7168 + 1*512 + o + j] +
                lds[7168 + 2*512 + o + j] + lds[7168 + 3*512 + o + j] + bias[ng];
      C[(size_t)(bm + m) * LDC + ng] = v;
    }
  }
#undef G2_LOAD
#undef G2_WRITE
}

// ============================================================================
// Attention (unchanged from round 1 — verified correct): only token 0 output
// matters. grid (16 heads, 8 l-tiles of 16 rows), 256 threads.
// ============================================================================
__global__ __launch_bounds__(256) void attn_kernel(
    const float* __restrict__ proj, float* __restrict__ ctx)
{
  __shared__ float ks[128][52];
  __shared__ float vs[128][52];
  int h  = blockIdx.x;
  int l0 = blockIdx.y * 16;
  int t  = threadIdx.x;

  for (int i = t; i < 128 * 12; i += 256) {
    int m  = i / 12;
    int dd = (i - m * 12) * 4;
    float4 kv = *(const float4*)&proj[(size_t)m * K3E + EMB     + h * DHD + dd];
    float4 vv = *(const float4*)&proj[(size_t)m * K3E + 2 * EMB + h * DHD + dd];
    *(float4*)&ks[m][dd] = kv;
    *(float4*)&vs[m][dd] = vv;
  }

  int l  = t >> 4;
  int g  = t & 15;
  int lg = l0 + l;
  const float scale = 0.14433756729740643f;  // 48^-0.5
  float q[48];
#pragma unroll
  for (int jj = 0; jj < 12; jj++) {
    float4 qv = *(const float4*)&proj[(size_t)lg * K3E + h * DHD + jj * 4];
    q[jj * 4 + 0] = qv.x * scale; q[jj * 4 + 1] = qv.y * scale;
    q[jj * 4 + 2] = qv.z * scale; q[jj * 4 + 3] = qv.w * scale;
  }
  __syncthreads();

  float sv[8];
  float smax = -1e30f;
#pragma unroll
  for (int jm = 0; jm < 8; jm++) {
    int m = g + jm * 16;
    float s = 0.0f;
#pragma unroll
    for (int dq = 0; dq < 12; dq++) {
      float4 kv = *(const float4*)&ks[m][dq * 4];
      s += q[dq * 4 + 0] * kv.x + q[dq * 4 + 1] * kv.y +
           q[dq * 4 + 2] * kv.z + q[dq * 4 + 3] * kv.w;
    }
    sv[jm] = s;
    smax = fmaxf(smax, s);
  }
#pragma unroll
  for (int off = 1; off < 16; off <<= 1) smax = fmaxf(smax, __shfl_xor(smax, off));
  float ssum = 0.0f;
#pragma unroll
  for (int jm = 0; jm < 8; jm++) { float e = __expf(sv[jm] - smax); sv[jm] = e; ssum += e; }
#pragma unroll
  for (int off = 1; off < 16; off <<= 1) ssum += __shfl_xor(ssum, off);
  float inv = 1.0f / ssum;
#pragma unroll
  for (int jm = 0; jm < 8; jm++) sv[jm] *= inv;

  float acc[48] = {};
#pragma unroll
  for (int jm = 0; jm < 8; jm++) {
    int m = g + jm * 16;
    float p = sv[jm];
#pragma unroll
    for (int dq = 0; dq < 12; dq++) {
      float4 vv = *(const float4*)&vs[m][dq * 4];
      acc[dq * 4 + 0] += p * vv.x; acc[dq * 4 + 1] += p * vv.y;
      acc[dq * 4 + 2] += p * vv.z; acc[dq * 4 + 3] += p * vv.w;
    }
  }

  {
    float buf[24];
    if (g & 8) {
#pragma unroll
      for (int d = 0; d < 24; d++) buf[d] = acc[d];
    } else {
#pragma unroll
      for (int d = 0; d < 24; d++) buf[d] = acc[d + 24];
    }
#pragma unroll
    for (int d = 0; d < 24; d++) buf[d] = __shfl_xor(buf[d], 8);
    if (g & 8) {
#pragma unroll
      for (int d = 0; d < 24; d++) acc[d] = acc[d + 24] + buf[d];
    } else {
#pragma unroll
      for (int d = 0; d < 24; d++) acc[d] = acc[d] + buf[d];
    }
  }
  {
    float buf[12];
    if (g & 4) {
#pragma unroll
      for (int d = 0; d < 12; d++) buf[d] = acc[d];
    } else {
#pragma unroll
      for (int d = 0; d < 12; d++) buf[d] = acc[d + 12];
    }
#pragma unroll
    for (int d = 0; d < 12; d++) buf[d] = __shfl_xor(buf[d], 4);
    if (g & 4) {
#pragma unroll
      for (int d = 0; d < 12; d++) acc[d] = acc[d + 12] + buf[d];
    } else {
#pragma unroll
      for (int d = 0; d < 12; d++) acc[d] = acc[d] + buf[d];
    }
  }
  {
    float buf[6];
    if (g & 2) {
#pragma unroll
      for (int d = 0; d < 6; d++) buf[d] = acc[d];
    } else {
#pragma unroll
      for (int d = 0; d < 6; d++) buf[d] = acc[d + 6];
    }
#pragma unroll
    for (int d = 0; d < 6; d++) buf[d] = __shfl_xor(buf[d], 2);
    if (g & 2) {
#pragma unroll
      for (int d = 0; d < 6; d++) acc[d] = acc[d + 6] + buf[d];
    } else {
#pragma unroll
      for (int d = 0; d < 6; d++) acc[d] = acc[d] + buf[d];
    }
  }
  {
    float buf[3];
    if (g & 1) {
#pragma unroll
      for (int d = 0; d < 3; d++) buf[d] = acc[d];
    } else {
#pragma unroll
      for (int d = 0; d < 3; d++) buf[d] = acc[d + 3];
    }
#pragma unroll
    for (int d = 0; d < 3; d++) buf[d] = __shfl_xor(buf[d], 1);
    if (g & 1) {
#pragma unroll
      for (int d = 0; d < 3; d++) acc[d] = acc[d + 3] + buf[d];
    } else {
#pragma unroll
      for (int d = 0; d < 3; d++) acc[d] = acc[d] + buf[d];
    }
  }
#pragma unroll
  for (int j = 0; j < 3; j++) {
    ctx[(size_t)lg * EMB + h * DHD + g * 3 + j] = acc[j];
  }
}

// ---------------------------------------------------------------------------
extern "C" void kernel_launch(void* const* d_in, const int* in_sizes, int n_in,
                              void* d_out, int out_size, void* d_ws, size_t ws_size,
                              hipStream_t stream) {
  const float* lhs   = (const float*)d_in[0];
  // d_in[1] sense_emb: dead — only attn_out[:,0,:] is used downstream.
  const int*   loc   = (const int*)  d_in[2];
  const float* w_in  = (const float*)d_in[3];
  const float* b_in  = (const float*)d_in[4];
  const float* w_out = (const float*)d_in[5];
  const float* b_out = (const float*)d_in[6];
  const float* w_lin = (const float*)d_in[7];
  const float* b_lin = (const float*)d_in[8];
  float* out = (float*)d_out;

  char* ws = (char*)d_ws;
  float* proj     = (float*)(ws);                       // 128*2304
  float* ctx      = (float*)(ws + 1179648);             // 128*768
  float* attn_out = (float*)(ws + 1179648 + 393216);    // 128*768

  gemm1_fused<<<dim3(36, 8), 256, 0, stream>>>(lhs, loc, w_in, b_in, proj);
  attn_kernel<<<dim3(NH, 8), 256, 0, stream>>>(proj, ctx);
  gemm_red<<<dim3(24, 8), 256, 0, stream>>>(ctx, w_out, b_out, attn_out, EMB, EMB);
  gemm_red<<<dim3(4, 8), 256, 0, stream>>>(attn_out, w_lin, b_lin, out, 100, 100);
}

// Round 4
// 51.696 us; speedup vs baseline: 2.2404x; 1.0977x over previous
//
#include <hip/hip_runtime.h>

#define SEQ 512
#define EMB 768
#define K3E 2304
#define DHD 48

// ============================================================================
// K1: proj[128,2304] = pun(gather) @ W_in^T + b_in
// Tile 16x32, grid (72,8)=576 blocks, 4 waves each owning K=192 (12xBK=16),
// wave-private double-buffered LDS, zero barriers in K-loop, 2x4 microtile.
// LDS 28KB: staging 4x1792 floats; reduction reuses wave regions post-barrier.
// ============================================================================
__global__ __launch_bounds__(256) void k1_gemm1(
    const float* __restrict__ lhs, const int* __restrict__ loc,
    const float* __restrict__ Bw, const float* __restrict__ bias,
    float* __restrict__ C)
{
  __shared__ float lds[7168];
  const int t  = threadIdx.x;
  const int w  = t >> 6, l = t & 63;
  const int bm = blockIdx.y * 16, bn = blockIdx.x * 32;
  const int tx = l & 7, ty = l >> 3;       // frag: n=tx*4, m=ty*2
  const int gm = l & 15, gq = l >> 4;      // A-staging: row, k-quad
  const int bl = l & 31, bh = l >> 5;      // B-staging: row, k-half
  const int kbase = w * 192;
  const int AW = w * 1792, BW = AW + 640;

  int locs[5]; int cnt = 0;
#pragma unroll
  for (int j = 0; j < 5; j++) {
    int v = loc[(bm + gm) * 5 + j];
    locs[j] = v; if (v >= 0) cnt++;
  }
  const float ginv = 1.0f / (float)cnt;
  const float* lrow = lhs + (size_t)(bm + gm) * SEQ * EMB;
  const float* brow = Bw + (size_t)(bn + bl) * EMB;

  float4 aF, bF0, bF1;

#define K1_LOAD(s) {                                                         \
    int k0 = kbase + (s) * 16;                                               \
    float sx=0.f, sy=0.f, sz=0.f, sw=0.f;                                    \
    _Pragma("unroll")                                                        \
    for (int j = 0; j < 5; j++) {                                            \
      int v = locs[j] >= 0 ? locs[j] : 0;                                    \
      float4 wv = *(const float4*)&lrow[(size_t)v * EMB + k0 + gq * 4];      \
      if (locs[j] >= 0) { sx+=wv.x; sy+=wv.y; sz+=wv.z; sw+=wv.w; }          \
    }                                                                        \
    aF = make_float4(sx*ginv, sy*ginv, sz*ginv, sw*ginv);                    \
    bF0 = *(const float4*)&brow[k0 + bh * 8 + 0];                            \
    bF1 = *(const float4*)&brow[k0 + bh * 8 + 4]; }

#define K1_WRITE(b) {                                                        \
    int Ab = AW + (b) * 320;                                                 \
    lds[Ab + (gq*4+0)*20 + gm] = aF.x;                                       \
    lds[Ab + (gq*4+1)*20 + gm] = aF.y;                                       \
    lds[Ab + (gq*4+2)*20 + gm] = aF.z;                                       \
    lds[Ab + (gq*4+3)*20 + gm] = aF.w;                                       \
    int Bb = BW + (b) * 576;                                                 \
    lds[Bb + (bh*8+0)*36 + bl] = bF0.x; lds[Bb + (bh*8+1)*36 + bl] = bF0.y;  \
    lds[Bb + (bh*8+2)*36 + bl] = bF0.z; lds[Bb + (bh*8+3)*36 + bl] = bF0.w;  \
    lds[Bb + (bh*8+4)*36 + bl] = bF1.x; lds[Bb + (bh*8+5)*36 + bl] = bF1.y;  \
    lds[Bb + (bh*8+6)*36 + bl] = bF1.z; lds[Bb + (bh*8+7)*36 + bl] = bF1.w; }

  float acc[2][4] = {};
  K1_LOAD(0); K1_WRITE(0);
  for (int s = 0; s < 12; s++) {
    int b = s & 1;
    if (s < 11) K1_LOAD(s + 1);
    int Ab = AW + b * 320, Bb = BW + b * 576;
#pragma unroll
    for (int kk = 0; kk < 16; kk++) {
      float2 a  = *(float2*)&lds[Ab + kk * 20 + ty * 2];
      float4 bb = *(float4*)&lds[Bb + kk * 36 + tx * 4];
      acc[0][0] += a.x*bb.x; acc[0][1] += a.x*bb.y; acc[0][2] += a.x*bb.z; acc[0][3] += a.x*bb.w;
      acc[1][0] += a.y*bb.x; acc[1][1] += a.y*bb.y; acc[1][2] += a.y*bb.z; acc[1][3] += a.y*bb.w;
    }
    if (s < 11) K1_WRITE(b ^ 1);
  }
#undef K1_LOAD
#undef K1_WRITE

  // partials into own (now dead) wave staging region; one barrier; reduce.
#pragma unroll
  for (int i = 0; i < 2; i++)
    *(float4*)&lds[AW + (ty*2 + i) * 32 + tx * 4] =
        make_float4(acc[i][0], acc[i][1], acc[i][2], acc[i][3]);
  __syncthreads();
  int o = t * 2;
  int m = o >> 5, n = o & 31;
  float2 s0 = *(float2*)&lds[0*1792 + o];
  float2 s1 = *(float2*)&lds[1*1792 + o];
  float2 s2 = *(float2*)&lds[2*1792 + o];
  float2 s3 = *(float2*)&lds[3*1792 + o];
  float2 bb2 = *(const float2*)&bias[bn + n];
  float2 r = make_float2(s0.x+s1.x+s2.x+s3.x+bb2.x, s0.y+s1.y+s2.y+s3.y+bb2.y);
  *(float2*)&C[(size_t)(bm + m) * K3E + bn + n] = r;
}

// ============================================================================
// K2: blocks 0..127: attention (head h = bx>>3, 16-row l-tile); only token 0.
//     blocks 128..295: W_comb[100,768] = w_lin @ w_out  (tile 16x32, wave
//     K-split like K1; B operand is w_out read row-major, staged to [k][n]).
// ============================================================================
__global__ __launch_bounds__(256) void k2_attn_wcomb(
    const float* __restrict__ proj, float* __restrict__ ctx,
    const float* __restrict__ wlin, const float* __restrict__ wout,
    float* __restrict__ wcomb)
{
  __shared__ float lds[13312];  // attn: ks 6656 + vs 6656; wcomb: 7168
  const int t = threadIdx.x;

  if (blockIdx.x < 128) {
    // ----------------------------- attention ------------------------------
    float* ks = lds;
    float* vs = lds + 6656;
    int h  = blockIdx.x >> 3;
    int l0 = (blockIdx.x & 7) * 16;

    for (int i = t; i < 128 * 12; i += 256) {
      int m  = i / 12;
      int dd = (i - m * 12) * 4;
      float4 kv = *(const float4*)&proj[(size_t)m * K3E + EMB     + h * DHD + dd];
      float4 vv = *(const float4*)&proj[(size_t)m * K3E + 2 * EMB + h * DHD + dd];
      *(float4*)&ks[m * 52 + dd] = kv;
      *(float4*)&vs[m * 52 + dd] = vv;
    }

    int l  = t >> 4;
    int g  = t & 15;
    int lg = l0 + l;
    const float scale = 0.14433756729740643f;  // 48^-0.5
    float q[48];
#pragma unroll
    for (int jj = 0; jj < 12; jj++) {
      float4 qv = *(const float4*)&proj[(size_t)lg * K3E + h * DHD + jj * 4];
      q[jj*4+0] = qv.x * scale; q[jj*4+1] = qv.y * scale;
      q[jj*4+2] = qv.z * scale; q[jj*4+3] = qv.w * scale;
    }
    __syncthreads();

    float sv[8];
    float smax = -1e30f;
#pragma unroll
    for (int jm = 0; jm < 8; jm++) {
      int m = g + jm * 16;
      float s = 0.0f;
#pragma unroll
      for (int dq = 0; dq < 12; dq++) {
        float4 kv = *(const float4*)&ks[m * 52 + dq * 4];
        s += q[dq*4+0]*kv.x + q[dq*4+1]*kv.y + q[dq*4+2]*kv.z + q[dq*4+3]*kv.w;
      }
      sv[jm] = s;
      smax = fmaxf(smax, s);
    }
#pragma unroll
    for (int off = 1; off < 16; off <<= 1) smax = fmaxf(smax, __shfl_xor(smax, off));
    float ssum = 0.0f;
#pragma unroll
    for (int jm = 0; jm < 8; jm++) { float e = __expf(sv[jm] - smax); sv[jm] = e; ssum += e; }
#pragma unroll
    for (int off = 1; off < 16; off <<= 1) ssum += __shfl_xor(ssum, off);
    float inv = 1.0f / ssum;
#pragma unroll
    for (int jm = 0; jm < 8; jm++) sv[jm] *= inv;

    float acc[48] = {};
#pragma unroll
    for (int jm = 0; jm < 8; jm++) {
      int m = g + jm * 16;
      float p = sv[jm];
#pragma unroll
      for (int dq = 0; dq < 12; dq++) {
        float4 vv = *(const float4*)&vs[m * 52 + dq * 4];
        acc[dq*4+0] += p*vv.x; acc[dq*4+1] += p*vv.y;
        acc[dq*4+2] += p*vv.z; acc[dq*4+3] += p*vv.w;
      }
    }

    {
      float buf[24];
      if (g & 8) {
#pragma unroll
        for (int d = 0; d < 24; d++) buf[d] = acc[d];
      } else {
#pragma unroll
        for (int d = 0; d < 24; d++) buf[d] = acc[d + 24];
      }
#pragma unroll
      for (int d = 0; d < 24; d++) buf[d] = __shfl_xor(buf[d], 8);
      if (g & 8) {
#pragma unroll
        for (int d = 0; d < 24; d++) acc[d] = acc[d + 24] + buf[d];
      } else {
#pragma unroll
        for (int d = 0; d < 24; d++) acc[d] = acc[d] + buf[d];
      }
    }
    {
      float buf[12];
      if (g & 4) {
#pragma unroll
        for (int d = 0; d < 12; d++) buf[d] = acc[d];
      } else {
#pragma unroll
        for (int d = 0; d < 12; d++) buf[d] = acc[d + 12];
      }
#pragma unroll
      for (int d = 0; d < 12; d++) buf[d] = __shfl_xor(buf[d], 4);
      if (g & 4) {
#pragma unroll
        for (int d = 0; d < 12; d++) acc[d] = acc[d + 12] + buf[d];
      } else {
#pragma unroll
        for (int d = 0; d < 12; d++) acc[d] = acc[d] + buf[d];
      }
    }
    {
      float buf[6];
      if (g & 2) {
#pragma unroll
        for (int d = 0; d < 6; d++) buf[d] = acc[d];
      } else {
#pragma unroll
        for (int d = 0; d < 6; d++) buf[d] = acc[d + 6];
      }
#pragma unroll
      for (int d = 0; d < 6; d++) buf[d] = __shfl_xor(buf[d], 2);
      if (g & 2) {
#pragma unroll
        for (int d = 0; d < 6; d++) acc[d] = acc[d + 6] + buf[d];
      } else {
#pragma unroll
        for (int d = 0; d < 6; d++) acc[d] = acc[d] + buf[d];
      }
    }
    {
      float buf[3];
      if (g & 1) {
#pragma unroll
        for (int d = 0; d < 3; d++) buf[d] = acc[d];
      } else {
#pragma unroll
        for (int d = 0; d < 3; d++) buf[d] = acc[d + 3];
      }
#pragma unroll
      for (int d = 0; d < 3; d++) buf[d] = __shfl_xor(buf[d], 1);
      if (g & 1) {
#pragma unroll
        for (int d = 0; d < 3; d++) acc[d] = acc[d + 3] + buf[d];
      } else {
#pragma unroll
        for (int d = 0; d < 3; d++) acc[d] = acc[d] + buf[d];
      }
    }
#pragma unroll
    for (int j = 0; j < 3; j++) {
      ctx[(size_t)lg * EMB + h * DHD + g * 3 + j] = acc[j];
    }
  } else {
    // ------------------------------ W_comb --------------------------------
    // W_comb[r][e] = sum_k wlin[r][k] * wout[k][e]
    const int c  = blockIdx.x - 128;
    const int bm = (c / 24) * 16;        // r-tile (0..96)
    const int bn = (c % 24) * 32;        // e-tile
    const int w  = t >> 6, l = t & 63;
    const int tx = l & 7, ty = l >> 3;
    const int am = l & 15, aq = l >> 4;
    const int wi = l >> 2;               // k-row 0..15
    const int j4 = (l & 3) * 8;          // e-offset 0,8,16,24
    const int kbase = w * 192;
    const int AW = w * 1792, BW = AW + 640;

    int arow_i = bm + am; if (arow_i > 99) arow_i = 99;
    const float* arow = wlin + (size_t)arow_i * EMB;

    float4 aF, bF0, bF1;

#define W_LOAD(s) {                                                          \
    int k0 = kbase + (s) * 16;                                               \
    aF  = *(const float4*)&arow[k0 + aq * 4];                                \
    const float* wr = wout + (size_t)(k0 + wi) * EMB + bn + j4;              \
    bF0 = *(const float4*)&wr[0];                                            \
    bF1 = *(const float4*)&wr[4]; }

#define W_WRITE(b) {                                                         \
    int Ab = AW + (b) * 320;                                                 \
    lds[Ab + (aq*4+0)*20 + am] = aF.x;                                       \
    lds[Ab + (aq*4+1)*20 + am] = aF.y;                                       \
    lds[Ab + (aq*4+2)*20 + am] = aF.z;                                       \
    lds[Ab + (aq*4+3)*20 + am] = aF.w;                                       \
    int Bb = BW + (b) * 576;                                                 \
    *(float4*)&lds[Bb + wi*36 + j4]     = bF0;                               \
    *(float4*)&lds[Bb + wi*36 + j4 + 4] = bF1; }

    float acc[2][4] = {};
    W_LOAD(0); W_WRITE(0);
    for (int s = 0; s < 12; s++) {
      int b = s & 1;
      if (s < 11) W_LOAD(s + 1);
      int Ab = AW + b * 320, Bb = BW + b * 576;
#pragma unroll
      for (int kk = 0; kk < 16; kk++) {
        float2 a  = *(float2*)&lds[Ab + kk * 20 + ty * 2];
        float4 bb = *(float4*)&lds[Bb + kk * 36 + tx * 4];
        acc[0][0] += a.x*bb.x; acc[0][1] += a.x*bb.y; acc[0][2] += a.x*bb.z; acc[0][3] += a.x*bb.w;
        acc[1][0] += a.y*bb.x; acc[1][1] += a.y*bb.y; acc[1][2] += a.y*bb.z; acc[1][3] += a.y*bb.w;
      }
      if (s < 11) W_WRITE(b ^ 1);
    }
#undef W_LOAD
#undef W_WRITE

#pragma unroll
    for (int i = 0; i < 2; i++)
      *(float4*)&lds[AW + (ty*2 + i) * 32 + tx * 4] =
          make_float4(acc[i][0], acc[i][1], acc[i][2], acc[i][3]);
    __syncthreads();
    int o = t * 2;
    int m = o >> 5, n = o & 31;
    if (bm + m < 100) {
      float2 s0 = *(float2*)&lds[0*1792 + o];
      float2 s1 = *(float2*)&lds[1*1792 + o];
      float2 s2 = *(float2*)&lds[2*1792 + o];
      float2 s3 = *(float2*)&lds[3*1792 + o];
      float2 r = make_float2(s0.x+s1.x+s2.x+s3.x, s0.y+s1.y+s2.y+s3.y);
      *(float2*)&wcomb[(size_t)(bm + m) * EMB + bn + n] = r;
    }
  }
}

// ============================================================================
// K3: res[128,100] = ctx @ W_comb^T + (wlin@b_out + b_lin)
// grid (4,8)=32 blocks, tile 16x32, wave K-split; bias_comb computed in-block.
// ============================================================================
__global__ __launch_bounds__(256) void k3_final(
    const float* __restrict__ A, const float* __restrict__ Bw,
    const float* __restrict__ wlin, const float* __restrict__ bout,
    const float* __restrict__ blin, float* __restrict__ C)
{
  __shared__ float lds[7200];  // staging 7168 + sbias 32
  const int t  = threadIdx.x;
  const int w  = t >> 6, l = t & 63;
  const int bm = blockIdx.y * 16, bn = blockIdx.x * 32;
  const int tx = l & 7, ty = l >> 3;
  const int am = l & 15, aq = l >> 4;
  const int bl = l & 31, bh = l >> 5;
  const int kbase = w * 192;
  const int AW = w * 1792, BW = AW + 640;

  // bias_comb[col] for this block's 32 cols: 8 lanes split K=768
  {
    int col = bn + (t >> 3);
    int ks  = (t & 7) * 96;
    float p = 0.f;
    if (col < 100) {
      const float* wr = wlin + (size_t)col * EMB + ks;
#pragma unroll
      for (int j = 0; j < 24; j++) {
        float4 wv = *(const float4*)&wr[j * 4];
        float4 bv = *(const float4*)&bout[ks + j * 4];
        p += wv.x*bv.x + wv.y*bv.y + wv.z*bv.z + wv.w*bv.w;
      }
    }
    p += __shfl_xor(p, 1); p += __shfl_xor(p, 2); p += __shfl_xor(p, 4);
    if ((t & 7) == 0) lds[7168 + (t >> 3)] = p + (col < 100 ? blin[col] : 0.f);
  }

  const float* arow = A + (size_t)(bm + am) * EMB;
  int brow_i = bn + bl; if (brow_i > 99) brow_i = 99;
  const float* brow = Bw + (size_t)brow_i * EMB;

  float4 aF, bF0, bF1;

#define F_LOAD(s) {                                                          \
    int k0 = kbase + (s) * 16;                                               \
    aF  = *(const float4*)&arow[k0 + aq * 4];                                \
    bF0 = *(const float4*)&brow[k0 + bh * 8 + 0];                            \
    bF1 = *(const float4*)&brow[k0 + bh * 8 + 4]; }

#define F_WRITE(b) {                                                         \
    int Ab = AW + (b) * 320;                                                 \
    lds[Ab + (aq*4+0)*20 + am] = aF.x;                                       \
    lds[Ab + (aq*4+1)*20 + am] = aF.y;                                       \
    lds[Ab + (aq*4+2)*20 + am] = aF.z;                                       \
    lds[Ab + (aq*4+3)*20 + am] = aF.w;                                       \
    int Bb = BW + (b) * 576;                                                 \
    lds[Bb + (bh*8+0)*36 + bl] = bF0.x; lds[Bb + (bh*8+1)*36 + bl] = bF0.y;  \
    lds[Bb + (bh*8+2)*36 + bl] = bF0.z; lds[Bb + (bh*8+3)*36 + bl] = bF0.w;  \
    lds[Bb + (bh*8+4)*36 + bl] = bF1.x; lds[Bb + (bh*8+5)*36 + bl] = bF1.y;  \
    lds[Bb + (bh*8+6)*36 + bl] = bF1.z; lds[Bb + (bh*8+7)*36 + bl] = bF1.w; }

  float acc[2][4] = {};
  F_LOAD(0); F_WRITE(0);
  for (int s = 0; s < 12; s++) {
    int b = s & 1;
    if (s < 11) F_LOAD(s + 1);
    int Ab = AW + b * 320, Bb = BW + b * 576;
#pragma unroll
    for (int kk = 0; kk < 16; kk++) {
      float2 a  = *(float2*)&lds[Ab + kk * 20 + ty * 2];
      float4 bb = *(float4*)&lds[Bb + kk * 36 + tx * 4];
      acc[0][0] += a.x*bb.x; acc[0][1] += a.x*bb.y; acc[0][2] += a.x*bb.z; acc[0][3] += a.x*bb.w;
      acc[1][0] += a.y*bb.x; acc[1][1] += a.y*bb.y; acc[1][2] += a.y*bb.z; acc[1][3] += a.y*bb.w;
    }
    if (s < 11) F_WRITE(b ^ 1);
  }
#undef F_LOAD
#undef F_WRITE

#pragma unroll
  for (int i = 0; i < 2; i++)
    *(float4*)&lds[AW + (ty*2 + i) * 32 + tx * 4] =
        make_float4(acc[i][0], acc[i][1], acc[i][2], acc[i][3]);
  __syncthreads();
  int o = t * 2;
  int m = o >> 5, n = o & 31;
#pragma unroll
  for (int j = 0; j < 2; j++) {
    int col = bn + n + j;
    if (col < 100) {
      float v = lds[0*1792 + o + j] + lds[1*1792 + o + j] +
                lds[2*1792 + o + j] + lds[3*1792 + o + j] + lds[7168 + n + j];
      C[(size_t)(bm + m) * 100 + col] = v;
    }
  }
}

// ---------------------------------------------------------------------------
extern "C" void kernel_launch(void* const* d_in, const int* in_sizes, int n_in,
                              void* d_out, int out_size, void* d_ws, size_t ws_size,
                              hipStream_t stream) {
  const float* lhs   = (const float*)d_in[0];
  // d_in[1] sense_emb: dead — only attn_out[:,0,:] is used downstream.
  const int*   loc   = (const int*)  d_in[2];
  const float* w_in  = (const float*)d_in[3];
  const float* b_in  = (const float*)d_in[4];
  const float* w_out = (const float*)d_in[5];
  const float* b_out = (const float*)d_in[6];
  const float* w_lin = (const float*)d_in[7];
  const float* b_lin = (const float*)d_in[8];
  float* out = (float*)d_out;

  char* ws = (char*)d_ws;
  float* proj  = (float*)(ws);                      // 128*2304 = 1179648 B
  float* ctx   = (float*)(ws + 1179648);            // 128*768  =  393216 B
  float* wcomb = (float*)(ws + 1179648 + 393216);   // 100*768  =  307200 B

  k1_gemm1<<<dim3(72, 8), 256, 0, stream>>>(lhs, loc, w_in, b_in, proj);
  k2_attn_wcomb<<<296, 256, 0, stream>>>(proj, ctx, w_lin, w_out, wcomb);
  k3_final<<<dim3(4, 8), 256, 0, stream>>>(ctx, wcomb, w_lin, b_out, b_lin, out);
}

// Round 5
// 45.932 us; speedup vs baseline: 2.5215x; 1.1255x over previous
//
#include <hip/hip_runtime.h>

#define SEQ 512
#define EMB 768
#define K3E 2304
#define DHD 48

// ============================================================================
// K0: pun[128,768] = masked gather-mean of lhs rows. 96 blocks x 256 thr,
// one float4 per thread: id -> (row, chunk).
// ============================================================================
__global__ __launch_bounds__(256) void k0_pun(
    const float* __restrict__ lhs, const int* __restrict__ loc,
    float* __restrict__ pun)
{
  int id = blockIdx.x * 256 + threadIdx.x;   // 24576 = 128 * 192
  int row = id / 192;
  int ch  = id - row * 192;
  int cnt = 0;
  float4 s = make_float4(0.f, 0.f, 0.f, 0.f);
#pragma unroll
  for (int j = 0; j < 5; j++) {
    int v = loc[row * 5 + j];
    if (v >= 0) {
      float4 wv = *(const float4*)&lhs[((size_t)row * SEQ + v) * EMB + ch * 4];
      s.x += wv.x; s.y += wv.y; s.z += wv.z; s.w += wv.w;
      cnt++;
    }
  }
  float inv = 1.0f / (float)cnt;
  *(float4*)&pun[(size_t)row * EMB + ch * 4] =
      make_float4(s.x * inv, s.y * inv, s.z * inv, s.w * inv);
}

// ============================================================================
// K1: blocks 0..575:  proj[128,2304] = pun @ W_in^T + b_in   (tile 16x32)
//     blocks 576..743: W_comb[100,768] = w_lin @ w_out       (tile 16x32)
// 512 thr = 8 waves, each wave owns K=96 (6 steps of BK=16), wave-private
// double-buffered LDS, zero barriers in the K-loop, 2x4 microtile.
// LDS: 8 x 1792 floats (A[2][16][20]=640 + B[2][16][36]=1152) = 56 KB.
// ============================================================================
__global__ __launch_bounds__(512, 4) void k1_gemm_wcomb(
    const float* __restrict__ pun, const float* __restrict__ Bw,
    const float* __restrict__ bias, float* __restrict__ C,
    const float* __restrict__ wlin, const float* __restrict__ wout,
    float* __restrict__ wcomb)
{
  __shared__ float lds[14336];
  const int t = threadIdx.x;
  const int w = t >> 6, l = t & 63;
  const int tx = l & 7, ty = l >> 3;       // frag: n=tx*4, m=ty*2
  const int gm = l & 15, gq = l >> 4;      // A-staging: row, k-quad
  const int kbase = w * 96;
  const int AW = w * 1792, BW = AW + 640;

  float4 aF, bF0, bF1;
  float acc[2][4] = {};

#define STAGE_A(b) {                                                         \
    int Ab = AW + (b) * 320;                                                 \
    lds[Ab + (gq*4+0)*20 + gm] = aF.x;                                       \
    lds[Ab + (gq*4+1)*20 + gm] = aF.y;                                       \
    lds[Ab + (gq*4+2)*20 + gm] = aF.z;                                       \
    lds[Ab + (gq*4+3)*20 + gm] = aF.w; }

#define INNER(b) {                                                           \
    int Ab = AW + (b) * 320, Bb = BW + (b) * 576;                            \
    _Pragma("unroll")                                                        \
    for (int kk = 0; kk < 16; kk++) {                                        \
      float2 a  = *(float2*)&lds[Ab + kk * 20 + ty * 2];                     \
      float4 bb = *(float4*)&lds[Bb + kk * 36 + tx * 4];                     \
      acc[0][0] += a.x*bb.x; acc[0][1] += a.x*bb.y;                          \
      acc[0][2] += a.x*bb.z; acc[0][3] += a.x*bb.w;                          \
      acc[1][0] += a.y*bb.x; acc[1][1] += a.y*bb.y;                          \
      acc[1][2] += a.y*bb.z; acc[1][3] += a.y*bb.w;                          \
    } }

  if (blockIdx.x < 576) {
    // ------------------------------ GEMM1 ---------------------------------
    const int c  = blockIdx.x;
    const int bm = (c / 72) * 16, bn = (c % 72) * 32;
    const int bl = l & 31, bh = l >> 5;    // B-staging: row, k-half
    const float* arow = pun + (size_t)(bm + gm) * EMB;
    const float* brow = Bw + (size_t)(bn + bl) * EMB;

#define G_LOAD(s) {                                                          \
    int k0 = kbase + (s) * 16;                                               \
    aF  = *(const float4*)&arow[k0 + gq * 4];                                \
    bF0 = *(const float4*)&brow[k0 + bh * 8 + 0];                            \
    bF1 = *(const float4*)&brow[k0 + bh * 8 + 4]; }

#define G_WRITE(b) {                                                         \
    STAGE_A(b)                                                               \
    int Bb = BW + (b) * 576;                                                 \
    lds[Bb + (bh*8+0)*36 + bl] = bF0.x; lds[Bb + (bh*8+1)*36 + bl] = bF0.y;  \
    lds[Bb + (bh*8+2)*36 + bl] = bF0.z; lds[Bb + (bh*8+3)*36 + bl] = bF0.w;  \
    lds[Bb + (bh*8+4)*36 + bl] = bF1.x; lds[Bb + (bh*8+5)*36 + bl] = bF1.y;  \
    lds[Bb + (bh*8+6)*36 + bl] = bF1.z; lds[Bb + (bh*8+7)*36 + bl] = bF1.w; }

    G_LOAD(0); G_WRITE(0);
    for (int s = 0; s < 6; s++) {
      int b = s & 1;
      if (s < 5) G_LOAD(s + 1);
      INNER(b);
      if (s < 5) G_WRITE(b ^ 1);
    }
#undef G_LOAD
#undef G_WRITE

#pragma unroll
    for (int i = 0; i < 2; i++)
      *(float4*)&lds[AW + (ty*2 + i) * 32 + tx * 4] =
          make_float4(acc[i][0], acc[i][1], acc[i][2], acc[i][3]);
    __syncthreads();
    int m = t >> 5, n = t & 31;
    float v = lds[0*1792 + t] + lds[1*1792 + t] + lds[2*1792 + t] + lds[3*1792 + t]
            + lds[4*1792 + t] + lds[5*1792 + t] + lds[6*1792 + t] + lds[7*1792 + t]
            + bias[bn + n];
    C[(size_t)(bm + m) * K3E + bn + n] = v;
  } else {
    // ------------------------------ W_comb --------------------------------
    const int cc = blockIdx.x - 576;
    const int bm = (cc / 24) * 16, bn = (cc % 24) * 32;
    const int wi = l >> 2;                 // k-row 0..15
    const int j4 = (l & 3) * 8;            // e-offset 0,8,16,24
    int arow_i = bm + gm; if (arow_i > 99) arow_i = 99;
    const float* arow = wlin + (size_t)arow_i * EMB;

#define W_LOAD(s) {                                                          \
    int k0 = kbase + (s) * 16;                                               \
    aF  = *(const float4*)&arow[k0 + gq * 4];                                \
    const float* wr = wout + (size_t)(k0 + wi) * EMB + bn + j4;              \
    bF0 = *(const float4*)&wr[0];                                            \
    bF1 = *(const float4*)&wr[4]; }

#define W_WRITE(b) {                                                         \
    STAGE_A(b)                                                               \
    int Bb = BW + (b) * 576;                                                 \
    *(float4*)&lds[Bb + wi*36 + j4]     = bF0;                               \
    *(float4*)&lds[Bb + wi*36 + j4 + 4] = bF1; }

    W_LOAD(0); W_WRITE(0);
    for (int s = 0; s < 6; s++) {
      int b = s & 1;
      if (s < 5) W_LOAD(s + 1);
      INNER(b);
      if (s < 5) W_WRITE(b ^ 1);
    }
#undef W_LOAD
#undef W_WRITE

#pragma unroll
    for (int i = 0; i < 2; i++)
      *(float4*)&lds[AW + (ty*2 + i) * 32 + tx * 4] =
          make_float4(acc[i][0], acc[i][1], acc[i][2], acc[i][3]);
    __syncthreads();
    int m = t >> 5, n = t & 31;
    if (bm + m < 100) {
      float v = lds[0*1792 + t] + lds[1*1792 + t] + lds[2*1792 + t] + lds[3*1792 + t]
              + lds[4*1792 + t] + lds[5*1792 + t] + lds[6*1792 + t] + lds[7*1792 + t];
      wcomb[(size_t)(bm + m) * EMB + bn + n] = v;
    }
  }
#undef STAGE_A
#undef INNER
}

// ============================================================================
// K2: attention (only token 0's output matters). grid (128): h = bx>>3,
// 16-row l-tile, 256 thr. Verified in rounds 1-4.
// ============================================================================
__global__ __launch_bounds__(256) void k2_attn(
    const float* __restrict__ proj, float* __restrict__ ctx)
{
  __shared__ float ks[128][52];
  __shared__ float vs[128][52];
  int h  = blockIdx.x >> 3;
  int l0 = (blockIdx.x & 7) * 16;
  int t  = threadIdx.x;

  for (int i = t; i < 128 * 12; i += 256) {
    int m  = i / 12;
    int dd = (i - m * 12) * 4;
    float4 kv = *(const float4*)&proj[(size_t)m * K3E + EMB     + h * DHD + dd];
    float4 vv = *(const float4*)&proj[(size_t)m * K3E + 2 * EMB + h * DHD + dd];
    *(float4*)&ks[m][dd] = kv;
    *(float4*)&vs[m][dd] = vv;
  }

  int l  = t >> 4;
  int g  = t & 15;
  int lg = l0 + l;
  const float scale = 0.14433756729740643f;  // 48^-0.5
  float q[48];
#pragma unroll
  for (int jj = 0; jj < 12; jj++) {
    float4 qv = *(const float4*)&proj[(size_t)lg * K3E + h * DHD + jj * 4];
    q[jj*4+0] = qv.x * scale; q[jj*4+1] = qv.y * scale;
    q[jj*4+2] = qv.z * scale; q[jj*4+3] = qv.w * scale;
  }
  __syncthreads();

  float sv[8];
  float smax = -1e30f;
#pragma unroll
  for (int jm = 0; jm < 8; jm++) {
    int m = g + jm * 16;
    float s = 0.0f;
#pragma unroll
    for (int dq = 0; dq < 12; dq++) {
      float4 kv = *(const float4*)&ks[m][dq * 4];
      s += q[dq*4+0]*kv.x + q[dq*4+1]*kv.y + q[dq*4+2]*kv.z + q[dq*4+3]*kv.w;
    }
    sv[jm] = s;
    smax = fmaxf(smax, s);
  }
#pragma unroll
  for (int off = 1; off < 16; off <<= 1) smax = fmaxf(smax, __shfl_xor(smax, off));
  float ssum = 0.0f;
#pragma unroll
  for (int jm = 0; jm < 8; jm++) { float e = __expf(sv[jm] - smax); sv[jm] = e; ssum += e; }
#pragma unroll
  for (int off = 1; off < 16; off <<= 1) ssum += __shfl_xor(ssum, off);
  float inv = 1.0f / ssum;
#pragma unroll
  for (int jm = 0; jm < 8; jm++) sv[jm] *= inv;

  float acc[48] = {};
#pragma unroll
  for (int jm = 0; jm < 8; jm++) {
    int m = g + jm * 16;
    float p = sv[jm];
#pragma unroll
    for (int dq = 0; dq < 12; dq++) {
      float4 vv = *(const float4*)&vs[m][dq * 4];
      acc[dq*4+0] += p*vv.x; acc[dq*4+1] += p*vv.y;
      acc[dq*4+2] += p*vv.z; acc[dq*4+3] += p*vv.w;
    }
  }

  {
    float buf[24];
    if (g & 8) {
#pragma unroll
      for (int d = 0; d < 24; d++) buf[d] = acc[d];
    } else {
#pragma unroll
      for (int d = 0; d < 24; d++) buf[d] = acc[d + 24];
    }
#pragma unroll
    for (int d = 0; d < 24; d++) buf[d] = __shfl_xor(buf[d], 8);
    if (g & 8) {
#pragma unroll
      for (int d = 0; d < 24; d++) acc[d] = acc[d + 24] + buf[d];
    } else {
#pragma unroll
      for (int d = 0; d < 24; d++) acc[d] = acc[d] + buf[d];
    }
  }
  {
    float buf[12];
    if (g & 4) {
#pragma unroll
      for (int d = 0; d < 12; d++) buf[d] = acc[d];
    } else {
#pragma unroll
      for (int d = 0; d < 12; d++) buf[d] = acc[d + 12];
    }
#pragma unroll
    for (int d = 0; d < 12; d++) buf[d] = __shfl_xor(buf[d], 4);
    if (g & 4) {
#pragma unroll
      for (int d = 0; d < 12; d++) acc[d] = acc[d + 12] + buf[d];
    } else {
#pragma unroll
      for (int d = 0; d < 12; d++) acc[d] = acc[d] + buf[d];
    }
  }
  {
    float buf[6];
    if (g & 2) {
#pragma unroll
      for (int d = 0; d < 6; d++) buf[d] = acc[d];
    } else {
#pragma unroll
      for (int d = 0; d < 6; d++) buf[d] = acc[d + 6];
    }
#pragma unroll
    for (int d = 0; d < 6; d++) buf[d] = __shfl_xor(buf[d], 2);
    if (g & 2) {
#pragma unroll
      for (int d = 0; d < 6; d++) acc[d] = acc[d + 6] + buf[d];
    } else {
#pragma unroll
      for (int d = 0; d < 6; d++) acc[d] = acc[d] + buf[d];
    }
  }
  {
    float buf[3];
    if (g & 1) {
#pragma unroll
      for (int d = 0; d < 3; d++) buf[d] = acc[d];
    } else {
#pragma unroll
      for (int d = 0; d < 3; d++) buf[d] = acc[d + 3];
    }
#pragma unroll
    for (int d = 0; d < 3; d++) buf[d] = __shfl_xor(buf[d], 1);
    if (g & 1) {
#pragma unroll
      for (int d = 0; d < 3; d++) acc[d] = acc[d + 3] + buf[d];
    } else {
#pragma unroll
      for (int d = 0; d < 3; d++) acc[d] = acc[d] + buf[d];
    }
  }
#pragma unroll
  for (int j = 0; j < 3; j++) {
    ctx[(size_t)lg * EMB + h * DHD + g * 3 + j] = acc[j];
  }
}

// ============================================================================
// K3: res[128,100] = ctx @ W_comb^T + (wlin@b_out + b_lin)
// grid (4,8)=32 blocks, 512 thr = 8 waves, wave K-split 8x96, tile 16x32.
// ============================================================================
__global__ __launch_bounds__(512, 4) void k3_final(
    const float* __restrict__ A, const float* __restrict__ Bw,
    const float* __restrict__ wlin, const float* __restrict__ bout,
    const float* __restrict__ blin, float* __restrict__ C)
{
  __shared__ float lds[14368];  // staging 14336 + sbias 32
  const int t = threadIdx.x;
  const int w = t >> 6, l = t & 63;
  const int bm = blockIdx.y * 16, bn = blockIdx.x * 32;
  const int tx = l & 7, ty = l >> 3;
  const int gm = l & 15, gq = l >> 4;
  const int bl = l & 31, bh = l >> 5;
  const int kbase = w * 96;
  const int AW = w * 1792, BW = AW + 640;

  // bias_comb for this block's 32 cols (threads 0..255)
  if (t < 256) {
    int col = bn + (t >> 3);
    int ks  = (t & 7) * 96;
    float p = 0.f;
    if (col < 100) {
      const float* wr = wlin + (size_t)col * EMB + ks;
#pragma unroll
      for (int j = 0; j < 24; j++) {
        float4 wv = *(const float4*)&wr[j * 4];
        float4 bv = *(const float4*)&bout[ks + j * 4];
        p += wv.x*bv.x + wv.y*bv.y + wv.z*bv.z + wv.w*bv.w;
      }
    }
    p += __shfl_xor(p, 1); p += __shfl_xor(p, 2); p += __shfl_xor(p, 4);
    if ((t & 7) == 0) lds[14336 + (t >> 3)] = p + (col < 100 ? blin[col] : 0.f);
  }

  const float* arow = A + (size_t)(bm + gm) * EMB;
  int brow_i = bn + bl; if (brow_i > 99) brow_i = 99;
  const float* brow = Bw + (size_t)brow_i * EMB;

  float4 aF, bF0, bF1;

#define F_LOAD(s) {                                                          \
    int k0 = kbase + (s) * 16;                                               \
    aF  = *(const float4*)&arow[k0 + gq * 4];                                \
    bF0 = *(const float4*)&brow[k0 + bh * 8 + 0];                            \
    bF1 = *(const float4*)&brow[k0 + bh * 8 + 4]; }

#define F_WRITE(b) {                                                         \
    int Ab = AW + (b) * 320;                                                 \
    lds[Ab + (gq*4+0)*20 + gm] = aF.x;                                       \
    lds[Ab + (gq*4+1)*20 + gm] = aF.y;                                       \
    lds[Ab + (gq*4+2)*20 + gm] = aF.z;                                       \
    lds[Ab + (gq*4+3)*20 + gm] = aF.w;                                       \
    int Bb = BW + (b) * 576;                                                 \
    lds[Bb + (bh*8+0)*36 + bl] = bF0.x; lds[Bb + (bh*8+1)*36 + bl] = bF0.y;  \
    lds[Bb + (bh*8+2)*36 + bl] = bF0.z; lds[Bb + (bh*8+3)*36 + bl] = bF0.w;  \
    lds[Bb + (bh*8+4)*36 + bl] = bF1.x; lds[Bb + (bh*8+5)*36 + bl] = bF1.y;  \
    lds[Bb + (bh*8+6)*36 + bl] = bF1.z; lds[Bb + (bh*8+7)*36 + bl] = bF1.w; }

  float acc[2][4] = {};
  F_LOAD(0); F_WRITE(0);
  for (int s = 0; s < 6; s++) {
    int b = s & 1;
    if (s < 5) F_LOAD(s + 1);
    int Ab = AW + b * 320, Bb = BW + b * 576;
#pragma unroll
    for (int kk = 0; kk < 16; kk++) {
      float2 a  = *(float2*)&lds[Ab + kk * 20 + ty * 2];
      float4 bb = *(float4*)&lds[Bb + kk * 36 + tx * 4];
      acc[0][0] += a.x*bb.x; acc[0][1] += a.x*bb.y; acc[0][2] += a.x*bb.z; acc[0][3] += a.x*bb.w;
      acc[1][0] += a.y*bb.x; acc[1][1] += a.y*bb.y; acc[1][2] += a.y*bb.z; acc[1][3] += a.y*bb.w;
    }
    if (s < 5) F_WRITE(b ^ 1);
  }
#undef F_LOAD
#undef F_WRITE

#pragma unroll
  for (int i = 0; i < 2; i++)
    *(float4*)&lds[AW + (ty*2 + i) * 32 + tx * 4] =
        make_float4(acc[i][0], acc[i][1], acc[i][2], acc[i][3]);
  __syncthreads();
  int m = t >> 5, n = t & 31;
  int col = bn + n;
  if (col < 100) {
    float v = lds[0*1792 + t] + lds[1*1792 + t] + lds[2*1792 + t] + lds[3*1792 + t]
            + lds[4*1792 + t] + lds[5*1792 + t] + lds[6*1792 + t] + lds[7*1792 + t]
            + lds[14336 + n];
    C[(size_t)(bm + m) * 100 + col] = v;
  }
}

// ---------------------------------------------------------------------------
extern "C" void kernel_launch(void* const* d_in, const int* in_sizes, int n_in,
                              void* d_out, int out_size, void* d_ws, size_t ws_size,
                              hipStream_t stream) {
  const float* lhs   = (const float*)d_in[0];
  // d_in[1] sense_emb: dead — only attn_out[:,0,:] is used downstream.
  const int*   loc   = (const int*)  d_in[2];
  const float* w_in  = (const float*)d_in[3];
  const float* b_in  = (const float*)d_in[4];
  const float* w_out = (const float*)d_in[5];
  const float* b_out = (const float*)d_in[6];
  const float* w_lin = (const float*)d_in[7];
  const float* b_lin = (const float*)d_in[8];
  float* out = (float*)d_out;

  char* ws = (char*)d_ws;
  float* pun   = (float*)(ws);                                // 128*768
  float* proj  = (float*)(ws + 393216);                       // 128*2304
  float* ctx   = (float*)(ws + 393216 + 1179648);             // 128*768
  float* wcomb = (float*)(ws + 393216 + 1179648 + 393216);    // 100*768

  k0_pun<<<96, 256, 0, stream>>>(lhs, loc, pun);
  k1_gemm_wcomb<<<744, 512, 0, stream>>>(pun, w_in, b_in, proj,
                                         w_lin, w_out, wcomb);
  k2_attn<<<128, 256, 0, stream>>>(proj, ctx);
  k3_final<<<dim3(4, 8), 512, 0, stream>>>(ctx, wcomb, w_lin, b_out, b_lin, out);
}